// Round 10
// baseline (112.808 us; speedup 1.0000x reference)
//
#include <hip/hip_runtime.h>

#define D_FEAT 32
#define BNODES 32             // nodes per coarse bucket
#define LOG_BN 5
#define NB_CAP 4096           // max buckets the bucket-scan supports (1024 thr x 4)
#define CHUNK 8192            // edges per binning chunk
#define BIG 1024              // threads for binning kernels
#define ECHUNK 1024           // edges per in-block sort chunk (phase 2)
#define CMASK 0x1FFFFu        // low 17 bits = col

// ---- pass A: per-chunk LDS histogram -> hist_all[chunk][bucket] (no atomics) ----
__global__ void __launch_bounds__(BIG) countA_kernel(const int* __restrict__ row,
                                                     int* __restrict__ hist_all,
                                                     int E, int nb) {
    extern __shared__ int hist[];
    int t = threadIdx.x;
    int blk = blockIdx.x;
    for (int i = t; i < nb; i += BIG) hist[i] = 0;
    __syncthreads();
    int s = blk * CHUNK;
    int e_end = min(E, s + CHUNK);
    int e = s + t * 4;
    for (; e + 3 < e_end; e += BIG * 4) {
        int4 r4 = *(const int4*)&row[e];
        atomicAdd(&hist[r4.x >> LOG_BN], 1);
        atomicAdd(&hist[r4.y >> LOG_BN], 1);
        atomicAdd(&hist[r4.z >> LOG_BN], 1);
        atomicAdd(&hist[r4.w >> LOG_BN], 1);
    }
    for (int e2 = e; e2 < e_end; ++e2)
        atomicAdd(&hist[row[e2] >> LOG_BN], 1);
    __syncthreads();
    int* dst = hist_all + (size_t)blk * nb;
    for (int i = t; i < nb; i += BIG) dst[i] = hist[i];
}

// ---- per-bucket prefix over chunks: hist_scan[chunk][b] = sum_{k<chunk} hist_all[k][b];
//      cnt[b] = bucket total. Thread-per-bucket, coalesced (block-major layout). ----
__global__ void colscan_kernel(const int* __restrict__ hist_all,
                               int* __restrict__ hist_scan,
                               int* __restrict__ cnt,
                               int nb, int nchunks) {
    int b = blockIdx.x * blockDim.x + threadIdx.x;
    if (b >= nb) return;
    int acc = 0;
    for (int k = 0; k < nchunks; ++k) {
        size_t idx = (size_t)k * nb + b;
        int v = hist_all[idx];
        hist_scan[idx] = acc;
        acc += v;
    }
    cnt[b] = acc;
}

// ---- exclusive scan of nb (<=4096) bucket totals, single 1024-thread block ----
__global__ void __launch_bounds__(1024) scan_kernel(const int* __restrict__ cnt,
                                                    int* __restrict__ offs, int nb) {
    __shared__ int sh[1024];
    int t = threadIdx.x;
    int base = t * 4;
    int v0 = (base + 0 < nb) ? cnt[base + 0] : 0;
    int v1 = (base + 1 < nb) ? cnt[base + 1] : 0;
    int v2 = (base + 2 < nb) ? cnt[base + 2] : 0;
    int v3 = (base + 3 < nb) ? cnt[base + 3] : 0;
    int s = v0 + v1 + v2 + v3;
    sh[t] = s;
    __syncthreads();
    for (int off = 1; off < 1024; off <<= 1) {
        int v = (t >= off) ? sh[t - off] : 0;
        __syncthreads();
        sh[t] += v;
        __syncthreads();
    }
    int p = sh[t] - s;
    if (base + 0 < nb) offs[base + 0] = p; p += v0;
    if (base + 1 < nb) offs[base + 1] = p; p += v1;
    if (base + 2 < nb) offs[base + 2] = p; p += v2;
    if (base + 3 < nb) offs[base + 3] = p;
}

// ---- pass B: load precomputed bases, single scatter pass (no re-histogram) ----
__global__ void __launch_bounds__(BIG) binB_kernel(const int* __restrict__ row,
                                                   const int* __restrict__ col,
                                                   const int* __restrict__ offs,
                                                   const int* __restrict__ hist_all,
                                                   const int* __restrict__ hist_scan,
                                                   unsigned* __restrict__ packed,
                                                   int E, int nb) {
    extern __shared__ int shmem[];
    int* base = shmem;       // global slot base for this (chunk,bucket)
    int* rem  = shmem + nb;  // countdown counter
    int t = threadIdx.x;
    int blk = blockIdx.x;
    const int* ha = hist_all + (size_t)blk * nb;
    const int* hs = hist_scan + (size_t)blk * nb;
    for (int i = t; i < nb; i += BIG) {
        base[i] = offs[i] + hs[i];
        rem[i]  = ha[i];
    }
    __syncthreads();

    int s = blk * CHUNK;
    int e_end = min(E, s + CHUNK);
    int e = s + t * 4;
    for (; e + 3 < e_end; e += BIG * 4) {
        int4 r4 = *(const int4*)&row[e];
        int4 c4 = *(const int4*)&col[e];
        int b, slot;
        b = r4.x >> LOG_BN; slot = base[b] + atomicAdd(&rem[b], -1) - 1;
        packed[slot] = ((unsigned)(r4.x & (BNODES - 1)) << 17) | (unsigned)c4.x;
        b = r4.y >> LOG_BN; slot = base[b] + atomicAdd(&rem[b], -1) - 1;
        packed[slot] = ((unsigned)(r4.y & (BNODES - 1)) << 17) | (unsigned)c4.y;
        b = r4.z >> LOG_BN; slot = base[b] + atomicAdd(&rem[b], -1) - 1;
        packed[slot] = ((unsigned)(r4.z & (BNODES - 1)) << 17) | (unsigned)c4.z;
        b = r4.w >> LOG_BN; slot = base[b] + atomicAdd(&rem[b], -1) - 1;
        packed[slot] = ((unsigned)(r4.w & (BNODES - 1)) << 17) | (unsigned)c4.w;
    }
    for (int e2 = e; e2 < e_end; ++e2) {
        int r = row[e2];
        int c = col[e2];
        int b = r >> LOG_BN;
        int slot = base[b] + atomicAdd(&rem[b], -1) - 1;
        packed[slot] = ((unsigned)(r & (BNODES - 1)) << 17) | (unsigned)c;
    }
}

// ---- phase 2: in-block counting sort + register-accumulated reduce ----
__global__ void __launch_bounds__(256) phase2_kernel(const float* __restrict__ x,
                                                     const unsigned* __restrict__ packed,
                                                     const int* __restrict__ offs,
                                                     const int* __restrict__ cnt,
                                                     float* __restrict__ out, int N) {
    __shared__ unsigned scol[ECHUNK];   // 4 KB: row-sorted packed entries
    __shared__ int hist[BNODES];
    __shared__ int hoff[BNODES];
    int t = threadIdx.x;
    int b = blockIdx.x;
    int s = offs[b];
    int n = cnt[b];
    int node = t >> 3;
    int j = t & 7;
    const float4* x4 = (const float4*)x;

    float4 acc = make_float4(0.f, 0.f, 0.f, 0.f);
    int mydeg = 0;

    for (int cs = 0; cs < n; cs += ECHUNK) {
        int m = min(ECHUNK, n - cs);
        if (t < BNODES) hist[t] = 0;
        __syncthreads();
        for (int i = t; i < m; i += 256)
            atomicAdd(&hist[packed[s + cs + i] >> 17], 1);
        __syncthreads();
        if (t < 64) {
            int v = (t < BNODES) ? hist[t] : 0;
            int sum = v;
            #pragma unroll
            for (int off = 1; off < BNODES; off <<= 1) {
                int w = __shfl_up(sum, off);
                if (t >= off) sum += w;
            }
            if (t < BNODES) hoff[t] = sum - v;
        }
        __syncthreads();
        int mcount = hist[node];
        int mbase = hoff[node];
        mydeg += mcount;
        __syncthreads();
        for (int i = t; i < m; i += 256) {
            unsigned p = packed[s + cs + i];
            int r = p >> 17;
            int slot = hoff[r] + atomicAdd(&hist[r], -1) - 1;
            scol[slot] = p;
        }
        __syncthreads();
        int i = 0;
        for (; i + 3 < mcount; i += 4) {
            unsigned c0 = scol[mbase + i + 0] & CMASK;
            unsigned c1 = scol[mbase + i + 1] & CMASK;
            unsigned c2 = scol[mbase + i + 2] & CMASK;
            unsigned c3 = scol[mbase + i + 3] & CMASK;
            float4 v0 = x4[c0 * 8 + j];
            float4 v1 = x4[c1 * 8 + j];
            float4 v2 = x4[c2 * 8 + j];
            float4 v3 = x4[c3 * 8 + j];
            acc.x += v0.x; acc.y += v0.y; acc.z += v0.z; acc.w += v0.w;
            acc.x += v1.x; acc.y += v1.y; acc.z += v1.z; acc.w += v1.w;
            acc.x += v2.x; acc.y += v2.y; acc.z += v2.z; acc.w += v2.w;
            acc.x += v3.x; acc.y += v3.y; acc.z += v3.z; acc.w += v3.w;
        }
        for (; i < mcount; ++i) {
            unsigned c = scol[mbase + i] & CMASK;
            float4 v = x4[c * 8 + j];
            acc.x += v.x; acc.y += v.y; acc.z += v.z; acc.w += v.w;
        }
        __syncthreads();
    }

    int gnode = b * BNODES + node;
    if (gnode < N) {
        float invd = 1.0f / fmaxf((float)mydeg, 1.0f);
        float4 v;
        v.x = acc.x * invd; v.y = acc.y * invd;
        v.z = acc.z * invd; v.w = acc.w * invd;
        ((float4*)out)[(size_t)gnode * 8 + j] = v;
    }
}

// ---------------- launch ----------------

extern "C" void kernel_launch(void* const* d_in, const int* in_sizes, int n_in,
                              void* d_out, int out_size, void* d_ws, size_t ws_size,
                              hipStream_t stream) {
    const float* x = (const float*)d_in[0];
    const int* edge_index = (const int*)d_in[1];

    int E = in_sizes[1] / 2;
    const int* row = edge_index;      // edge_index[0]
    const int* col = edge_index + E;  // edge_index[1]
    int N = in_sizes[0] / D_FEAT;

    float* out = (float*)d_out;

    int nb = (N + BNODES - 1) / BNODES;   // 3125 buckets
    if (nb > NB_CAP) nb = NB_CAP;
    int nchunks = (E + CHUNK - 1) / CHUNK;  // 196

    // ws layout (ints): cnt[nb] | offs[nb] | hist_all[nchunks*nb]
    //                 | hist_scan[nchunks*nb] | packed[E]      (~11.4 MB of 256 MB)
    int* cnt       = (int*)d_ws;
    int* offs      = cnt + nb;
    int* hist_all  = offs + nb;
    int* hist_scan = hist_all + (size_t)nchunks * nb;
    unsigned* packed = (unsigned*)(hist_scan + (size_t)nchunks * nb);

    size_t lds1 = (size_t)nb * sizeof(int);
    size_t lds2 = (size_t)2 * nb * sizeof(int);

    countA_kernel<<<nchunks, BIG, lds1, stream>>>(row, hist_all, E, nb);
    colscan_kernel<<<(nb + 255) / 256, 256, 0, stream>>>(hist_all, hist_scan, cnt, nb, nchunks);
    scan_kernel<<<1, 1024, 0, stream>>>(cnt, offs, nb);
    binB_kernel<<<nchunks, BIG, lds2, stream>>>(row, col, offs, hist_all, hist_scan, packed, E, nb);
    phase2_kernel<<<nb, 256, 0, stream>>>(x, packed, offs, cnt, out, N);
}

// Round 11
// 76.552 us; speedup vs baseline: 1.4736x; 1.4736x over previous
//
#include <hip/hip_runtime.h>

#define D_FEAT 32
#define BNODES 32             // nodes per coarse bucket
#define LOG_BN 5
#define NB_CAP 4096           // max buckets the bucket-scan supports (1024 thr x 4)
#define CHUNK 8192            // edges per binning chunk
#define BIG 1024              // threads for binning kernels
#define ECHUNK 1024           // edges per in-block sort chunk (phase 2)
#define CMASK 0x1FFFFu        // low 17 bits = col

// ---- zero cnt+gfill (adjacent, 2*nb ints) ----
__global__ void zero_kernel(int* __restrict__ p, int n) {
    int i = blockIdx.x * blockDim.x + threadIdx.x;
    if (i < n) p[i] = 0;
}

// ---- pass A: per-chunk LDS histogram -> hist_all[chunk][*] + bucket totals ----
__global__ void __launch_bounds__(BIG) countA_kernel(const int* __restrict__ row,
                                                     int* __restrict__ hist_all,
                                                     int* __restrict__ cnt,
                                                     int E, int nb) {
    extern __shared__ int hist[];
    int t = threadIdx.x;
    int blk = blockIdx.x;
    for (int i = t; i < nb; i += BIG) hist[i] = 0;
    __syncthreads();
    int s = blk * CHUNK;
    int e_end = min(E, s + CHUNK);
    int e = s + t * 4;
    for (; e + 3 < e_end; e += BIG * 4) {
        int4 r4 = *(const int4*)&row[e];
        atomicAdd(&hist[r4.x >> LOG_BN], 1);
        atomicAdd(&hist[r4.y >> LOG_BN], 1);
        atomicAdd(&hist[r4.z >> LOG_BN], 1);
        atomicAdd(&hist[r4.w >> LOG_BN], 1);
    }
    for (int e2 = e; e2 < e_end; ++e2)
        atomicAdd(&hist[row[e2] >> LOG_BN], 1);
    __syncthreads();
    int* dst = hist_all + (size_t)blk * nb;
    for (int i = t; i < nb; i += BIG) {
        int h = hist[i];
        dst[i] = h;
        if (h) atomicAdd(&cnt[i], h);
    }
}

// ---- exclusive scan of nb (<=4096) bucket totals, single 1024-thread block ----
__global__ void __launch_bounds__(1024) scan_kernel(const int* __restrict__ cnt,
                                                    int* __restrict__ offs, int nb) {
    __shared__ int sh[1024];
    int t = threadIdx.x;
    int base = t * 4;
    int v0 = (base + 0 < nb) ? cnt[base + 0] : 0;
    int v1 = (base + 1 < nb) ? cnt[base + 1] : 0;
    int v2 = (base + 2 < nb) ? cnt[base + 2] : 0;
    int v3 = (base + 3 < nb) ? cnt[base + 3] : 0;
    int s = v0 + v1 + v2 + v3;
    sh[t] = s;
    __syncthreads();
    for (int off = 1; off < 1024; off <<= 1) {
        int v = (t >= off) ? sh[t - off] : 0;
        __syncthreads();
        sh[t] += v;
        __syncthreads();
    }
    int p = sh[t] - s;
    if (base + 0 < nb) offs[base + 0] = p; p += v0;
    if (base + 1 < nb) offs[base + 1] = p; p += v1;
    if (base + 2 < nb) offs[base + 2] = p; p += v2;
    if (base + 3 < nb) offs[base + 3] = p;
}

// ---- pass B: load precomputed counts, reserve via gfill, single scatter pass ----
__global__ void __launch_bounds__(BIG) binB_kernel(const int* __restrict__ row,
                                                   const int* __restrict__ col,
                                                   const int* __restrict__ offs,
                                                   const int* __restrict__ hist_all,
                                                   int* __restrict__ gfill,
                                                   unsigned* __restrict__ packed,
                                                   int E, int nb) {
    extern __shared__ int shmem[];
    int* base = shmem;       // global slot base for this (chunk,bucket)
    int* rem  = shmem + nb;  // countdown counter
    int t = threadIdx.x;
    int blk = blockIdx.x;
    const int* ha = hist_all + (size_t)blk * nb;
    for (int i = t; i < nb; i += BIG) {
        int h = ha[i];
        rem[i] = h;
        base[i] = h ? (offs[i] + atomicAdd(&gfill[i], h)) : 0;
    }
    __syncthreads();

    int s = blk * CHUNK;
    int e_end = min(E, s + CHUNK);
    int e = s + t * 4;
    for (; e + 3 < e_end; e += BIG * 4) {
        int4 r4 = *(const int4*)&row[e];
        int4 c4 = *(const int4*)&col[e];
        int b, slot;
        b = r4.x >> LOG_BN; slot = base[b] + atomicAdd(&rem[b], -1) - 1;
        packed[slot] = ((unsigned)(r4.x & (BNODES - 1)) << 17) | (unsigned)c4.x;
        b = r4.y >> LOG_BN; slot = base[b] + atomicAdd(&rem[b], -1) - 1;
        packed[slot] = ((unsigned)(r4.y & (BNODES - 1)) << 17) | (unsigned)c4.y;
        b = r4.z >> LOG_BN; slot = base[b] + atomicAdd(&rem[b], -1) - 1;
        packed[slot] = ((unsigned)(r4.z & (BNODES - 1)) << 17) | (unsigned)c4.z;
        b = r4.w >> LOG_BN; slot = base[b] + atomicAdd(&rem[b], -1) - 1;
        packed[slot] = ((unsigned)(r4.w & (BNODES - 1)) << 17) | (unsigned)c4.w;
    }
    for (int e2 = e; e2 < e_end; ++e2) {
        int r = row[e2];
        int c = col[e2];
        int b = r >> LOG_BN;
        int slot = base[b] + atomicAdd(&rem[b], -1) - 1;
        packed[slot] = ((unsigned)(r & (BNODES - 1)) << 17) | (unsigned)c;
    }
}

// ---- phase 2: in-block counting sort + register-accumulated reduce ----
__global__ void __launch_bounds__(256) phase2_kernel(const float* __restrict__ x,
                                                     const unsigned* __restrict__ packed,
                                                     const int* __restrict__ offs,
                                                     const int* __restrict__ cnt,
                                                     float* __restrict__ out, int N) {
    __shared__ unsigned scol[ECHUNK];   // 4 KB: row-sorted packed entries
    __shared__ int hist[BNODES];
    __shared__ int hoff[BNODES];
    int t = threadIdx.x;
    int b = blockIdx.x;
    int s = offs[b];
    int n = cnt[b];
    int node = t >> 3;
    int j = t & 7;
    const float4* x4 = (const float4*)x;

    float4 acc = make_float4(0.f, 0.f, 0.f, 0.f);
    int mydeg = 0;

    for (int cs = 0; cs < n; cs += ECHUNK) {
        int m = min(ECHUNK, n - cs);
        if (t < BNODES) hist[t] = 0;
        __syncthreads();
        for (int i = t; i < m; i += 256)
            atomicAdd(&hist[packed[s + cs + i] >> 17], 1);
        __syncthreads();
        if (t < 64) {
            int v = (t < BNODES) ? hist[t] : 0;
            int sum = v;
            #pragma unroll
            for (int off = 1; off < BNODES; off <<= 1) {
                int w = __shfl_up(sum, off);
                if (t >= off) sum += w;
            }
            if (t < BNODES) hoff[t] = sum - v;
        }
        __syncthreads();
        int mcount = hist[node];
        int mbase = hoff[node];
        mydeg += mcount;
        __syncthreads();
        for (int i = t; i < m; i += 256) {
            unsigned p = packed[s + cs + i];
            int r = p >> 17;
            int slot = hoff[r] + atomicAdd(&hist[r], -1) - 1;
            scol[slot] = p;
        }
        __syncthreads();
        int i = 0;
        for (; i + 3 < mcount; i += 4) {
            unsigned c0 = scol[mbase + i + 0] & CMASK;
            unsigned c1 = scol[mbase + i + 1] & CMASK;
            unsigned c2 = scol[mbase + i + 2] & CMASK;
            unsigned c3 = scol[mbase + i + 3] & CMASK;
            float4 v0 = x4[c0 * 8 + j];
            float4 v1 = x4[c1 * 8 + j];
            float4 v2 = x4[c2 * 8 + j];
            float4 v3 = x4[c3 * 8 + j];
            acc.x += v0.x; acc.y += v0.y; acc.z += v0.z; acc.w += v0.w;
            acc.x += v1.x; acc.y += v1.y; acc.z += v1.z; acc.w += v1.w;
            acc.x += v2.x; acc.y += v2.y; acc.z += v2.z; acc.w += v2.w;
            acc.x += v3.x; acc.y += v3.y; acc.z += v3.z; acc.w += v3.w;
        }
        for (; i < mcount; ++i) {
            unsigned c = scol[mbase + i] & CMASK;
            float4 v = x4[c * 8 + j];
            acc.x += v.x; acc.y += v.y; acc.z += v.z; acc.w += v.w;
        }
        __syncthreads();
    }

    int gnode = b * BNODES + node;
    if (gnode < N) {
        float invd = 1.0f / fmaxf((float)mydeg, 1.0f);
        float4 v;
        v.x = acc.x * invd; v.y = acc.y * invd;
        v.z = acc.z * invd; v.w = acc.w * invd;
        ((float4*)out)[(size_t)gnode * 8 + j] = v;
    }
}

// ---------------- launch ----------------

extern "C" void kernel_launch(void* const* d_in, const int* in_sizes, int n_in,
                              void* d_out, int out_size, void* d_ws, size_t ws_size,
                              hipStream_t stream) {
    const float* x = (const float*)d_in[0];
    const int* edge_index = (const int*)d_in[1];

    int E = in_sizes[1] / 2;
    const int* row = edge_index;      // edge_index[0]
    const int* col = edge_index + E;  // edge_index[1]
    int N = in_sizes[0] / D_FEAT;

    float* out = (float*)d_out;

    int nb = (N + BNODES - 1) / BNODES;     // 3125 buckets
    if (nb > NB_CAP) nb = NB_CAP;
    int nchunks = (E + CHUNK - 1) / CHUNK;  // 196

    // ws layout (ints): cnt[nb] | gfill[nb] | offs[nb] | hist_all[nchunks*nb] | packed[E]
    int* cnt      = (int*)d_ws;
    int* gfill    = cnt + nb;
    int* offs     = gfill + nb;
    int* hist_all = offs + nb;
    unsigned* packed = (unsigned*)(hist_all + (size_t)nchunks * nb);

    int nzero = 2 * nb;
    zero_kernel<<<(nzero + 255) / 256, 256, 0, stream>>>(cnt, nzero);

    size_t lds1 = (size_t)nb * sizeof(int);
    size_t lds2 = (size_t)2 * nb * sizeof(int);

    countA_kernel<<<nchunks, BIG, lds1, stream>>>(row, hist_all, cnt, E, nb);
    scan_kernel<<<1, 1024, 0, stream>>>(cnt, offs, nb);
    binB_kernel<<<nchunks, BIG, lds2, stream>>>(row, col, offs, hist_all, gfill, packed, E, nb);
    phase2_kernel<<<nb, 256, 0, stream>>>(x, packed, offs, cnt, out, N);
}

// Round 12
// 57.343 us; speedup vs baseline: 1.9673x; 1.3350x over previous
//
#include <hip/hip_runtime.h>

#define D_FEAT 32
#define BNODES 32             // nodes per coarse bucket
#define LOG_BN 5
#define CHUNK 8192            // edges per build block (8 per thread)
#define BIG 1024              // threads for build kernel
#define ECHUNK 1024           // edges per in-block sort chunk (phase 2)
#define CAP 2048              // fixed packed slots per bucket (mean load 512)
#define CMASK 0x1FFFFu        // low 17 bits = col

// ---- zero per-bucket fill counters ----
__global__ void zero_kernel(int* __restrict__ p, int n) {
    int i = blockIdx.x * blockDim.x + threadIdx.x;
    if (i < n) p[i] = 0;
}

// ---- single-pass build: stage edges in regs, LDS hist, reserve fixed-CAP
//      region per bucket, emit packed. Replaces countA+scan+binB. ----
__global__ void __launch_bounds__(BIG) build_kernel(const int* __restrict__ row,
                                                    const int* __restrict__ col,
                                                    int* __restrict__ cnt,
                                                    unsigned* __restrict__ packed,
                                                    int E, int nb) {
    extern __shared__ int shmem[];
    int* hist = shmem;       // nb: per-chunk histogram, then countdown
    int* base = shmem + nb;  // nb: global slot base for this (chunk,bucket)
    int t = threadIdx.x;
    int blk = blockIdx.x;
    for (int i = t; i < nb; i += BIG) hist[i] = 0;

    int s = blk * CHUNK;
    int e_end = min(E, s + CHUNK);
    int e0 = s + t * 4;
    int e1 = e0 + BIG * 4;

    // stage 8 edges per thread in registers (single read of row+col)
    int4 r0, c0, r1, c1;
    if (s + CHUNK <= E) {
        r0 = *(const int4*)&row[e0];
        c0 = *(const int4*)&col[e0];
        r1 = *(const int4*)&row[e1];
        c1 = *(const int4*)&col[e1];
    } else {
        // tail chunk: guarded scalar loads, -1 = invalid sentinel
        r0.x = (e0 + 0 < e_end) ? row[e0 + 0] : -1;
        r0.y = (e0 + 1 < e_end) ? row[e0 + 1] : -1;
        r0.z = (e0 + 2 < e_end) ? row[e0 + 2] : -1;
        r0.w = (e0 + 3 < e_end) ? row[e0 + 3] : -1;
        c0.x = (e0 + 0 < e_end) ? col[e0 + 0] : 0;
        c0.y = (e0 + 1 < e_end) ? col[e0 + 1] : 0;
        c0.z = (e0 + 2 < e_end) ? col[e0 + 2] : 0;
        c0.w = (e0 + 3 < e_end) ? col[e0 + 3] : 0;
        r1.x = (e1 + 0 < e_end) ? row[e1 + 0] : -1;
        r1.y = (e1 + 1 < e_end) ? row[e1 + 1] : -1;
        r1.z = (e1 + 2 < e_end) ? row[e1 + 2] : -1;
        r1.w = (e1 + 3 < e_end) ? row[e1 + 3] : -1;
        c1.x = (e1 + 0 < e_end) ? col[e1 + 0] : 0;
        c1.y = (e1 + 1 < e_end) ? col[e1 + 1] : 0;
        c1.z = (e1 + 2 < e_end) ? col[e1 + 2] : 0;
        c1.w = (e1 + 3 < e_end) ? col[e1 + 3] : 0;
    }
    __syncthreads();  // hist zeroed

    // LDS histogram
    if (r0.x >= 0) atomicAdd(&hist[r0.x >> LOG_BN], 1);
    if (r0.y >= 0) atomicAdd(&hist[r0.y >> LOG_BN], 1);
    if (r0.z >= 0) atomicAdd(&hist[r0.z >> LOG_BN], 1);
    if (r0.w >= 0) atomicAdd(&hist[r0.w >> LOG_BN], 1);
    if (r1.x >= 0) atomicAdd(&hist[r1.x >> LOG_BN], 1);
    if (r1.y >= 0) atomicAdd(&hist[r1.y >> LOG_BN], 1);
    if (r1.z >= 0) atomicAdd(&hist[r1.z >> LOG_BN], 1);
    if (r1.w >= 0) atomicAdd(&hist[r1.w >> LOG_BN], 1);
    __syncthreads();

    // reserve fixed-capacity region slots: one global atomic per (chunk,bucket)
    for (int i = t; i < nb; i += BIG) {
        int h = hist[i];
        base[i] = h ? (i * CAP + atomicAdd(&cnt[i], h)) : 0;
    }
    __syncthreads();

    // emit from registers (hist counts down to assign unique slots)
    #define EMIT(rr, cc)                                                      \
        if ((rr) >= 0) {                                                      \
            int b_ = (rr) >> LOG_BN;                                          \
            int slot_ = base[b_] + atomicAdd(&hist[b_], -1) - 1;              \
            packed[slot_] = ((unsigned)((rr) & (BNODES - 1)) << 17) |         \
                            (unsigned)(cc);                                   \
        }
    EMIT(r0.x, c0.x); EMIT(r0.y, c0.y); EMIT(r0.z, c0.z); EMIT(r0.w, c0.w);
    EMIT(r1.x, c1.x); EMIT(r1.y, c1.y); EMIT(r1.z, c1.z); EMIT(r1.w, c1.w);
    #undef EMIT
}

// ---- phase 2: in-block counting sort + register-accumulated reduce ----
__global__ void __launch_bounds__(256) phase2_kernel(const float* __restrict__ x,
                                                     const unsigned* __restrict__ packed,
                                                     const int* __restrict__ cnt,
                                                     float* __restrict__ out, int N) {
    __shared__ unsigned scol[ECHUNK];   // 4 KB: row-sorted packed entries
    __shared__ int hist[BNODES];
    __shared__ int hoff[BNODES];
    int t = threadIdx.x;
    int b = blockIdx.x;
    int s = b * CAP;
    int n = cnt[b];
    int node = t >> 3;
    int j = t & 7;
    const float4* x4 = (const float4*)x;

    float4 acc = make_float4(0.f, 0.f, 0.f, 0.f);
    int mydeg = 0;

    for (int cs = 0; cs < n; cs += ECHUNK) {
        int m = min(ECHUNK, n - cs);
        if (t < BNODES) hist[t] = 0;
        __syncthreads();
        for (int i = t; i < m; i += 256)
            atomicAdd(&hist[packed[s + cs + i] >> 17], 1);
        __syncthreads();
        if (t < 64) {
            int v = (t < BNODES) ? hist[t] : 0;
            int sum = v;
            #pragma unroll
            for (int off = 1; off < BNODES; off <<= 1) {
                int w = __shfl_up(sum, off);
                if (t >= off) sum += w;
            }
            if (t < BNODES) hoff[t] = sum - v;
        }
        __syncthreads();
        int mcount = hist[node];
        int mbase = hoff[node];
        mydeg += mcount;
        __syncthreads();
        for (int i = t; i < m; i += 256) {
            unsigned p = packed[s + cs + i];
            int r = p >> 17;
            int slot = hoff[r] + atomicAdd(&hist[r], -1) - 1;
            scol[slot] = p;
        }
        __syncthreads();
        int i = 0;
        for (; i + 3 < mcount; i += 4) {
            unsigned c0 = scol[mbase + i + 0] & CMASK;
            unsigned c1 = scol[mbase + i + 1] & CMASK;
            unsigned c2 = scol[mbase + i + 2] & CMASK;
            unsigned c3 = scol[mbase + i + 3] & CMASK;
            float4 v0 = x4[c0 * 8 + j];
            float4 v1 = x4[c1 * 8 + j];
            float4 v2 = x4[c2 * 8 + j];
            float4 v3 = x4[c3 * 8 + j];
            acc.x += v0.x; acc.y += v0.y; acc.z += v0.z; acc.w += v0.w;
            acc.x += v1.x; acc.y += v1.y; acc.z += v1.z; acc.w += v1.w;
            acc.x += v2.x; acc.y += v2.y; acc.z += v2.z; acc.w += v2.w;
            acc.x += v3.x; acc.y += v3.y; acc.z += v3.z; acc.w += v3.w;
        }
        for (; i < mcount; ++i) {
            unsigned c = scol[mbase + i] & CMASK;
            float4 v = x4[c * 8 + j];
            acc.x += v.x; acc.y += v.y; acc.z += v.z; acc.w += v.w;
        }
        __syncthreads();
    }

    int gnode = b * BNODES + node;
    if (gnode < N) {
        float invd = 1.0f / fmaxf((float)mydeg, 1.0f);
        float4 v;
        v.x = acc.x * invd; v.y = acc.y * invd;
        v.z = acc.z * invd; v.w = acc.w * invd;
        ((float4*)out)[(size_t)gnode * 8 + j] = v;
    }
}

// ---------------- launch ----------------

extern "C" void kernel_launch(void* const* d_in, const int* in_sizes, int n_in,
                              void* d_out, int out_size, void* d_ws, size_t ws_size,
                              hipStream_t stream) {
    const float* x = (const float*)d_in[0];
    const int* edge_index = (const int*)d_in[1];

    int E = in_sizes[1] / 2;
    const int* row = edge_index;      // edge_index[0]
    const int* col = edge_index + E;  // edge_index[1]
    int N = in_sizes[0] / D_FEAT;

    float* out = (float*)d_out;

    int nb = (N + BNODES - 1) / BNODES;     // 3125 buckets
    int nchunks = (E + CHUNK - 1) / CHUNK;  // 196

    // ws layout (ints): cnt[nb] (64-aligned pad) | packed[nb*CAP]  (~25.6 MB)
    int* cnt = (int*)d_ws;
    unsigned* packed = (unsigned*)(cnt + ((nb + 63) & ~63));

    zero_kernel<<<(nb + 255) / 256, 256, 0, stream>>>(cnt, nb);

    size_t lds = (size_t)2 * nb * sizeof(int);
    build_kernel<<<nchunks, BIG, lds, stream>>>(row, col, cnt, packed, E, nb);
    phase2_kernel<<<nb, 256, 0, stream>>>(x, packed, cnt, out, N);
}